// Round 5
// baseline (6276.365 us; speedup 1.0000x reference)
//
#include <hip/hip_runtime.h>
#include <stdint.h>

#define B_ 64
#define T_ 512
#define D_ 512
#define U_ 1024
#define TC 32
#define NCH 16   // chunks per layer

typedef unsigned short u16;
typedef unsigned long long u64;
typedef u16 ushort8  __attribute__((ext_vector_type(8)));
typedef __bf16 bf16x8 __attribute__((ext_vector_type(8)));
typedef float f32x4  __attribute__((ext_vector_type(4)));

static __device__ __forceinline__ u16 f2bf(float f) {
  unsigned u = __builtin_bit_cast(unsigned, f);
  u += 0x7FFFu + ((u >> 16) & 1u);      // round-to-nearest-even
  return (u16)(u >> 16);
}
static __device__ __forceinline__ float bf2f(u16 h) {
  unsigned u = ((unsigned)h) << 16;
  return __builtin_bit_cast(float, u);
}

// ---------------- prep: pack weights [K][4096] f32 -> [n'][K] bf16, n' = (u<<2)|g ----------------

__global__ __launch_bounds__(256) void pack_wt(const float* __restrict__ src,
                                               u16* __restrict__ dst, int K) {
  __shared__ float tile[32][33];
  int n0 = blockIdx.x * 32, k0 = blockIdx.y * 32;
  int tx = threadIdx.x, ty = threadIdx.y;  // 32 x 8
#pragma unroll
  for (int r = 0; r < 4; ++r) {
    int k = k0 + ty + r * 8;
    tile[ty + r * 8][tx] = src[(long)k * 4096 + n0 + tx];
  }
  __syncthreads();
#pragma unroll
  for (int r = 0; r < 4; ++r) {
    int n = n0 + ty + r * 8;
    int np = ((n & 1023) << 2) | (n >> 10);
    dst[(long)np * K + k0 + tx] = f2bf(tile[tx][ty + r * 8]);
  }
}

__global__ __launch_bounds__(256) void pack_bias(const float* __restrict__ b1,
                                                 const float* __restrict__ b2,
                                                 float* __restrict__ bp) {
  int n = blockIdx.x * 256 + threadIdx.x;  // 0..4095
  int np = ((n & 1023) << 2) | (n >> 10);
  bp[np] = b1[n];
  bp[4096 + np] = b2[n];
}

// ---------------- zx GEMM: zx[b*TC+tt][n'] = A[row] @ Wp[n',:]^T + bias[n'] ----------------

template <bool AF32>
__global__ __launch_bounds__(512) void zx_gemm(const void* __restrict__ Av, long sB, long sT,
                                               int K, const u16* __restrict__ Bp,
                                               const float* __restrict__ biasp,
                                               float* __restrict__ zxo) {
  __shared__ __align__(16) u16 Als[128][72];
  __shared__ __align__(16) u16 Bls[128][72];
  const int tid = threadIdx.x;
  const int mt = blockIdx.x, nt = blockIdx.y;
  const int l = tid & 63, w = tid >> 6;
  const int wm = w >> 2, wn = w & 3;              // wave tile: 64 rows x 32 cols
  const int sr = tid >> 2, skq = (tid & 3) * 16;  // staging: row, k-offset (16 elems)

  const int gr = mt * 128 + sr;                   // global M row = b*TC + tt
  const int b = gr >> 5, tt = gr & 31;
  const long abase = (long)b * sB + (long)tt * sT;
  const float* Af = (const float*)Av;
  const u16* Ah = (const u16*)Av;

  const int nc = K >> 6;
  float4 raf[4];
  ushort8 rah[2];
  ushort8 rb[2];

  auto gload = [&](int ch) {
    long k0 = (long)ch << 6;
    if constexpr (AF32) {
#pragma unroll
      for (int i = 0; i < 4; ++i)
        raf[i] = *reinterpret_cast<const float4*>(Af + abase + k0 + skq + i * 4);
    } else {
#pragma unroll
      for (int i = 0; i < 2; ++i)
        rah[i] = *reinterpret_cast<const ushort8*>(Ah + abase + k0 + skq + i * 8);
    }
#pragma unroll
    for (int i = 0; i < 2; ++i)
      rb[i] = *reinterpret_cast<const ushort8*>(Bp + (long)(nt * 128 + sr) * K + k0 + skq + i * 8);
  };

  f32x4 acc[4][2];
#pragma unroll
  for (int fm = 0; fm < 4; ++fm)
#pragma unroll
    for (int fn = 0; fn < 2; ++fn) acc[fm][fn] = (f32x4){0.f, 0.f, 0.f, 0.f};

  gload(0);
  for (int ch = 0; ch < nc; ++ch) {
    __syncthreads();
    if constexpr (AF32) {
      const float* pr = (const float*)raf;
      ushort8 lo, hi;
#pragma unroll
      for (int j = 0; j < 8; ++j) { lo[j] = f2bf(pr[j]); hi[j] = f2bf(pr[8 + j]); }
      *reinterpret_cast<ushort8*>(&Als[sr][skq]) = lo;
      *reinterpret_cast<ushort8*>(&Als[sr][skq + 8]) = hi;
    } else {
      *reinterpret_cast<ushort8*>(&Als[sr][skq]) = rah[0];
      *reinterpret_cast<ushort8*>(&Als[sr][skq + 8]) = rah[1];
    }
    *reinterpret_cast<ushort8*>(&Bls[sr][skq]) = rb[0];
    *reinterpret_cast<ushort8*>(&Bls[sr][skq + 8]) = rb[1];
    __syncthreads();
    if (ch + 1 < nc) gload(ch + 1);
#pragma unroll
    for (int ks = 0; ks < 2; ++ks) {
#pragma unroll
      for (int fm = 0; fm < 4; ++fm) {
        bf16x8 a = __builtin_bit_cast(bf16x8,
            *reinterpret_cast<const ushort8*>(&Als[wm * 64 + fm * 16 + (l & 15)][ks * 32 + (l >> 4) * 8]));
#pragma unroll
        for (int fn = 0; fn < 2; ++fn) {
          bf16x8 bb = __builtin_bit_cast(bf16x8,
              *reinterpret_cast<const ushort8*>(&Bls[wn * 32 + fn * 16 + (l & 15)][ks * 32 + (l >> 4) * 8]));
          acc[fm][fn] = __builtin_amdgcn_mfma_f32_16x16x32_bf16(a, bb, acc[fm][fn], 0, 0, 0);
        }
      }
    }
  }

#pragma unroll
  for (int fm = 0; fm < 4; ++fm)
#pragma unroll
    for (int fn = 0; fn < 2; ++fn) {
      int col = nt * 128 + wn * 32 + fn * 16 + (l & 15);
      float bv = biasp[col];
#pragma unroll
      for (int j = 0; j < 4; ++j) {
        int row = mt * 128 + wm * 64 + fm * 16 + (l >> 4) * 4 + j;
        zxo[(long)row * 4096 + col] = acc[fm][fn][j] + bv;
      }
    }
}

// ---------------- persistent dual-layer LSTM chunk (cooperative, fenceless flag sync) ----------------
// 256 blocks: [layer(2)] x [batch-quarter(4)] x [col-group(32) of 32 units = 128 gate-cols].
// h exchange + flags via relaxed AGENT-scope atomics (bypass non-coherent XCD L2).
// R / zx / h1seq use normal cached paths; NO fences -> L2 stays hot.

__global__ __launch_bounds__(512) void lstm_chunk(
    const float* __restrict__ zx1, const u16* __restrict__ R1p, float* __restrict__ c1v,
    u16* __restrict__ h1_0, u16* __restrict__ h1_1, u16* __restrict__ h1s,
    const float* __restrict__ zx2, const u16* __restrict__ R2p, float* __restrict__ c2v,
    u16* __restrict__ h2_0, u16* __restrict__ h2_1,
    unsigned* __restrict__ flag1, unsigned* __restrict__ flag2,
    int g01, int g02, int act1, int act2) {
  const int layer = blockIdx.x >> 7;
  if (layer ? (!act2) : (!act1)) return;

  __shared__ __align__(16) u16 Als[16][1032];       // full h-slice rows for this step (33 KB)
  __shared__ __align__(16) u16 Bls[2][128][136];    // R chunk double buffer (70 KB)
  __shared__ float Zls[16][132];                    // z tile f32 (8.4 KB)

  const float* zx = layer ? zx2 : zx1;
  const u16* Rp   = layer ? R2p : R1p;
  float* cv       = layer ? c2v : c1v;
  u16* hb0        = layer ? h2_0 : h1_0;
  u16* hb1        = layer ? h2_1 : h1_1;
  unsigned* flag  = layer ? flag2 : flag1;
  const int g0    = layer ? g02 : g01;

  const int lb = blockIdx.x & 127;
  const int q = lb >> 5;          // batch quarter: rows q*16..+15
  const int cg = lb & 31;         // col group: units cg*32..+31, gate-cols cg*128..+127
  const int n0 = cg * 128;
  const int u0 = cg * 32;

  const int tid = threadIdx.x;
  const int l = tid & 63, w = tid >> 6;

  // A staging: 16 rows x 1024 shorts, thread: row tid>>5, 32 shorts (8 x u64) at (tid&31)*32
  const int tArow = tid >> 5, tAoff = (tid & 31) * 32;
  // B staging: 128 rows x 128k per chunk, thread: row tid>>2, 32 shorts at (tid&3)*32
  const int tBrow = tid >> 2, tBoff = (tid & 3) * 32;
  // gates: thread (b row 0..15, unit 0..31)
  const int tgb = tid >> 5, tgun = tid & 31;
  const int bq = q * 16 + tgb;
  const int ug = u0 + tgun;

  float creg = cv[(long)bq * U_ + ug];

  ushort8 rbv[4];
  auto gloadB = [&](int ch) {
#pragma unroll
    for (int i = 0; i < 4; ++i)
      rbv[i] = *reinterpret_cast<const ushort8*>(Rp + (long)(n0 + tBrow) * U_ + ch * 128 + tBoff + i * 8);
  };

  for (int tt = 0; tt < TC; ++tt) {
    const int g = g0 + tt;

    // ---- wait for h(g-1) complete (all 128 blocks of this layer) ----
    if (g > 0) {
      if (tid == 0) {
        while (__hip_atomic_load(&flag[g - 1], __ATOMIC_RELAXED, __HIP_MEMORY_SCOPE_AGENT) < 128u)
          __builtin_amdgcn_s_sleep(2);
      }
      __syncthreads();
    }

    // ---- stage A = h(g-1) rows q*16..+15 via agent loads (coherence-point-fresh) ----
    const u16* hr = (g & 1) ? hb0 : hb1;   // h(g-1) lives in buf[(g-1)&1]
    u16* hw       = (g & 1) ? hb1 : hb0;   // h(g)   goes to  buf[g&1]
    {
      u64* src = (u64*)(hr + (long)(q * 16 + tArow) * U_ + tAoff);
#pragma unroll
      for (int i = 0; i < 8; ++i) {   // 8 x u64 = 32 shorts (FIX: was 4 -> half of Als stale)
        u64 v = __hip_atomic_load(src + i, __ATOMIC_RELAXED, __HIP_MEMORY_SCOPE_AGENT);
        *reinterpret_cast<u64*>(&Als[tArow][tAoff + i * 4]) = v;
      }
    }

    // ---- z-tile: 16 x 128, K=1024 in 8 chunks of BK=128, Bls double-buffered ----
    f32x4 acc = {0.f, 0.f, 0.f, 0.f};
    gloadB(0);
#pragma unroll
    for (int i = 0; i < 4; ++i)
      *reinterpret_cast<ushort8*>(&Bls[0][tBrow][tBoff + i * 8]) = rbv[i];
    for (int ch = 0; ch < 8; ++ch) {
      if (ch < 7) gloadB(ch + 1);
      __syncthreads();                    // Als + Bls[ch&1] visible; old reads done
      if (ch < 7) {
#pragma unroll
        for (int i = 0; i < 4; ++i)
          *reinterpret_cast<ushort8*>(&Bls[(ch + 1) & 1][tBrow][tBoff + i * 8]) = rbv[i];
      }
#pragma unroll
      for (int ks = 0; ks < 4; ++ks) {
        bf16x8 a = __builtin_bit_cast(bf16x8,
            *reinterpret_cast<const ushort8*>(&Als[l & 15][ch * 128 + ks * 32 + (l >> 4) * 8]));
        bf16x8 bb = __builtin_bit_cast(bf16x8,
            *reinterpret_cast<const ushort8*>(&Bls[ch & 1][w * 16 + (l & 15)][ks * 32 + (l >> 4) * 8]));
        acc = __builtin_amdgcn_mfma_f32_16x16x32_bf16(a, bb, acc, 0, 0, 0);
      }
    }

    // ---- acc -> Zls: wave w covers cols w*16; D row=(l>>4)*4+j, col=l&15 ----
    {
      int r0 = (l >> 4) * 4, col = w * 16 + (l & 15);
#pragma unroll
      for (int j = 0; j < 4; ++j) Zls[r0 + j][col] = acc[j];
    }
    __syncthreads();

    // ---- gates: thread (tgb, tgun) ----
    {
      f32x4 zr = *reinterpret_cast<const f32x4*>(&Zls[tgb][tgun * 4]);
      f32x4 zv = *reinterpret_cast<const f32x4*>(zx + ((long)bq * TC + tt) * 4096 + n0 + tgun * 4);
      float zi = zr[0] + zv[0], zf = zr[1] + zv[1], zg = zr[2] + zv[2], zo = zr[3] + zv[3];
      float ig = 1.f / (1.f + expf(-zi));
      float fg = 1.f / (1.f + expf(-zf));
      float og = 1.f / (1.f + expf(-zo));
      creg = fg * creg + ig * zg;
      u16 hv = f2bf(og * creg);
      // pair adjacent units into u32 agent store (even tgun stores)
      unsigned hvn = __shfl_down((unsigned)hv, 1, 64);
      if ((tgun & 1) == 0) {
        unsigned pv = (unsigned)hv | (hvn << 16);
        __hip_atomic_store((unsigned*)(hw + (long)bq * U_ + ug), pv,
                           __ATOMIC_RELAXED, __HIP_MEMORY_SCOPE_AGENT);
      }
      if (layer == 0) h1s[((long)bq * T_ + g) * U_ + ug] = hv;
    }

    // ---- publish: drain stores, then arrive ----
    asm volatile("s_waitcnt vmcnt(0)" ::: "memory");
    __syncthreads();
    if (tid == 0)
      __hip_atomic_fetch_add(&flag[g], 1u, __ATOMIC_RELAXED, __HIP_MEMORY_SCOPE_AGENT);
  }

  cv[(long)bq * U_ + ug] = creg;
}

// ---------------- LayerNorm + tanh ----------------

__global__ __launch_bounds__(256) void ln_chunk(const u16* __restrict__ h1seq, int t0,
                                                const float* __restrict__ gamma,
                                                const float* __restrict__ beta,
                                                u16* __restrict__ dst) {
  __shared__ float sbuf[8];
  int row = blockIdx.x;            // 0..2047
  int b = row >> 5, tt = row & 31;
  const u16* src = h1seq + ((long)b * T_ + t0 + tt) * U_;
  u16* drow = dst + (long)row * U_;
  float x[4];
#pragma unroll
  for (int j = 0; j < 4; ++j) x[j] = bf2f(src[threadIdx.x + 256 * j]);
  float s = x[0] + x[1] + x[2] + x[3];
  for (int o = 32; o > 0; o >>= 1) s += __shfl_down(s, o, 64);
  if ((threadIdx.x & 63) == 0) sbuf[threadIdx.x >> 6] = s;
  __syncthreads();
  float mu = (sbuf[0] + sbuf[1] + sbuf[2] + sbuf[3]) * (1.f / 1024.f);
  float d[4], s2 = 0.f;
#pragma unroll
  for (int j = 0; j < 4; ++j) { d[j] = x[j] - mu; s2 += d[j] * d[j]; }
  for (int o = 32; o > 0; o >>= 1) s2 += __shfl_down(s2, o, 64);
  if ((threadIdx.x & 63) == 0) sbuf[4 + (threadIdx.x >> 6)] = s2;
  __syncthreads();
  float inv = rsqrtf((sbuf[4] + sbuf[5] + sbuf[6] + sbuf[7]) * (1.f / 1024.f) + 1e-3f);
#pragma unroll
  for (int j = 0; j < 4; ++j) {
    int u = threadIdx.x + 256 * j;
    drow[u] = f2bf(tanhf(d[j] * inv * gamma[u] + beta[u]));
  }
}

__global__ __launch_bounds__(256) void ln_tanh_final(const u16* __restrict__ h2,
                                                     const float* __restrict__ gamma,
                                                     const float* __restrict__ beta,
                                                     float* __restrict__ out) {
  __shared__ float sbuf[8];
  const u16* row = h2 + (long)blockIdx.x * U_;
  float x[4];
#pragma unroll
  for (int j = 0; j < 4; ++j) x[j] = bf2f(row[threadIdx.x + 256 * j]);
  float s = x[0] + x[1] + x[2] + x[3];
  for (int o = 32; o > 0; o >>= 1) s += __shfl_down(s, o, 64);
  if ((threadIdx.x & 63) == 0) sbuf[threadIdx.x >> 6] = s;
  __syncthreads();
  float mu = (sbuf[0] + sbuf[1] + sbuf[2] + sbuf[3]) * (1.f / 1024.f);
  float d[4], s2 = 0.f;
#pragma unroll
  for (int j = 0; j < 4; ++j) { d[j] = x[j] - mu; s2 += d[j] * d[j]; }
  for (int o = 32; o > 0; o >>= 1) s2 += __shfl_down(s2, o, 64);
  if ((threadIdx.x & 63) == 0) sbuf[4 + (threadIdx.x >> 6)] = s2;
  __syncthreads();
  float inv = rsqrtf((sbuf[4] + sbuf[5] + sbuf[6] + sbuf[7]) * (1.f / 1024.f) + 1e-3f);
#pragma unroll
  for (int j = 0; j < 4; ++j) {
    int u = threadIdx.x + 256 * j;
    out[(long)blockIdx.x * U_ + u] = tanhf(d[j] * inv * gamma[u] + beta[u]);
  }
}

// ---------------- launcher ----------------

extern "C" void kernel_launch(void* const* d_in, const int* in_sizes, int n_in,
                              void* d_out, int out_size, void* d_ws, size_t ws_size,
                              hipStream_t stream) {
  const float* x      = (const float*)d_in[0];
  const float* W1     = (const float*)d_in[1];
  const float* R1     = (const float*)d_in[2];
  const float* b1     = (const float*)d_in[3];
  const float* gamma1 = (const float*)d_in[4];
  const float* beta1  = (const float*)d_in[5];
  const float* W2     = (const float*)d_in[6];
  const float* R2     = (const float*)d_in[7];
  const float* b2     = (const float*)d_in[8];
  const float* gamma2 = (const float*)d_in[9];
  const float* beta2  = (const float*)d_in[10];
  float* out = (float*)d_out;

  char* base = (char*)d_ws;
  size_t off = 0;
  auto alloc = [&](size_t bytes) -> void* {
    void* p = base + off;
    off += (bytes + 255) & ~(size_t)255;
    return p;
  };
  u16*      Wp1   = (u16*)alloc((size_t)4096 * D_ * 2);           // 4 MB
  u16*      Rp1   = (u16*)alloc((size_t)4096 * U_ * 2);           // 8 MB
  u16*      Wp2   = (u16*)alloc((size_t)4096 * U_ * 2);           // 8 MB
  u16*      Rp2   = (u16*)alloc((size_t)4096 * U_ * 2);           // 8 MB
  float*    biasp = (float*)alloc((size_t)2 * 4096 * 4);          // 32 KB
  float*    zxA   = (float*)alloc((size_t)B_ * TC * 4096 * 4);    // 33.5 MB
  float*    zxB   = (float*)alloc((size_t)B_ * TC * 4096 * 4);    // 33.5 MB
  u16*      h1seq = (u16*)alloc((size_t)B_ * T_ * U_ * 2);        // 67 MB
  u16*      h1ln  = (u16*)alloc((size_t)B_ * TC * U_ * 2);        // 4.2 MB
  float*    c1    = (float*)alloc((size_t)B_ * U_ * 4);
  float*    c2    = (float*)alloc((size_t)B_ * U_ * 4);
  u16*      h1a   = (u16*)alloc((size_t)B_ * U_ * 2);
  u16*      h1b   = (u16*)alloc((size_t)B_ * U_ * 2);
  u16*      h2a   = (u16*)alloc((size_t)B_ * U_ * 2);
  u16*      h2b   = (u16*)alloc((size_t)B_ * U_ * 2);
  unsigned* flag1 = (unsigned*)alloc((size_t)T_ * 4);
  unsigned* flag2 = (unsigned*)alloc((size_t)T_ * 4);

  // prep
  pack_wt<<<dim3(128, 16), dim3(32, 8), 0, stream>>>(W1, Wp1, D_);
  pack_wt<<<dim3(128, 32), dim3(32, 8), 0, stream>>>(R1, Rp1, U_);
  pack_wt<<<dim3(128, 32), dim3(32, 8), 0, stream>>>(W2, Wp2, U_);
  pack_wt<<<dim3(128, 32), dim3(32, 8), 0, stream>>>(R2, Rp2, U_);
  pack_bias<<<16, 256, 0, stream>>>(b1, b2, biasp);
  hipMemsetAsync(c1, 0, (size_t)B_ * U_ * 4, stream);
  hipMemsetAsync(c2, 0, (size_t)B_ * U_ * 4, stream);
  hipMemsetAsync(h1b, 0, (size_t)B_ * U_ * 2, stream);   // h(-1) lives in buf1
  hipMemsetAsync(h2b, 0, (size_t)B_ * U_ * 2, stream);
  hipMemsetAsync(flag1, 0, (size_t)T_ * 4, stream);
  hipMemsetAsync(flag2, 0, (size_t)T_ * 4, stream);

  // pipelined phases: phase p = layer1 chunk p + layer2 chunk p-1
  for (int p = 0; p <= NCH; ++p) {
    int act1 = (p < NCH), act2 = (p >= 1);
    if (act1)
      zx_gemm<true><<<dim3(16, 32), 512, 0, stream>>>(
          (const void*)(x + (long)p * TC * D_), (long)T_ * D_, (long)D_, D_, Wp1, biasp, zxA);
    if (act2) {
      ln_chunk<<<B_ * TC, 256, 0, stream>>>(h1seq, (p - 1) * TC, gamma1, beta1, h1ln);
      zx_gemm<false><<<dim3(16, 32), 512, 0, stream>>>(
          (const void*)h1ln, (long)TC * U_, (long)U_, U_, Wp2, biasp + 4096, zxB);
    }
    const float* p_zx1 = zxA; const u16* p_R1 = Rp1; float* p_c1 = c1;
    u16* p_h10 = h1a; u16* p_h11 = h1b; u16* p_h1s = h1seq;
    const float* p_zx2 = zxB; const u16* p_R2 = Rp2; float* p_c2 = c2;
    u16* p_h20 = h2a; u16* p_h21 = h2b;
    unsigned* p_f1 = flag1; unsigned* p_f2 = flag2;
    int p_g01 = p * TC, p_g02 = (p - 1) * TC, p_a1 = act1, p_a2 = act2;
    void* args[17] = {&p_zx1, &p_R1, &p_c1, &p_h10, &p_h11, &p_h1s,
                      &p_zx2, &p_R2, &p_c2, &p_h20, &p_h21,
                      &p_f1, &p_f2, &p_g01, &p_g02, &p_a1, &p_a2};
    hipLaunchCooperativeKernel((void*)lstm_chunk, dim3(256), dim3(512), args, 0, stream);
  }
  // h(511) lives in buf[511&1] = buf1
  ln_tanh_final<<<B_, 256, 0, stream>>>(h2b, gamma2, beta2, out);
}